// Round 13
// baseline (1343.178 us; speedup 1.0000x reference)
//
#include <hip/hip_runtime.h>

typedef unsigned short u16;
typedef unsigned int u32;
typedef __attribute__((ext_vector_type(8))) short bf16x8;
typedef __attribute__((ext_vector_type(4))) float f32x4;

#define GLOBAL_AS __attribute__((address_space(1)))
#define LDS_AS __attribute__((address_space(3)))

__device__ __forceinline__ float b2f(u16 u) {
    union { float f; u32 i; } v; v.i = ((u32)u) << 16; return v.f;
}
__device__ __forceinline__ u16 f2b(float f) {
    union { float f; u32 i; } v; v.f = f;
    u32 i = v.i;
    u32 r = (i + 0x7FFFu + ((i >> 16) & 1u)) >> 16;
    return (u16)r;
}
__device__ __forceinline__ float sigm(float x) { return 1.f / (1.f + expf(-x)); }

// ---------------------------------------------------------------------------
// Batched f32 -> bf16 converter: 9 segments in one launch (verified R8)
// ---------------------------------------------------------------------------
struct CvtJobs {
    const float* src[9];
    u16*         dst[9];
    int          end4[9];
};
__global__ void cvt_multi(CvtJobs jobs, int total4)
{
    for (int id = blockIdx.x * 256 + threadIdx.x; id < total4;
         id += gridDim.x * 256) {
        int s = 0;
        while (id >= jobs.end4[s]) ++s;
        int base = (s == 0) ? 0 : jobs.end4[s - 1];
        int i = id - base;
        float4 v = ((const float4*)jobs.src[s])[i];
        u32 w0 = (u32)f2b(v.x) | ((u32)f2b(v.y) << 16);
        u32 w1 = (u32)f2b(v.z) | ((u32)f2b(v.w) << 16);
        ((u32*)jobs.dst[s])[i * 2]     = w0;
        ((u32*)jobs.dst[s])[i * 2 + 1] = w1;
    }
}

// ---------------------------------------------------------------------------
// Generic GEMM: C[M,N] = A[M,K] @ W[N,K]^T + bias[N]   (m97-pattern, verified)
// ---------------------------------------------------------------------------
template<bool LEAKY, bool REMAP>
__global__ __launch_bounds__(256)
void gemm_bt(const u16* __restrict__ A, const u16* __restrict__ W,
             const float* __restrict__ bias,
             float* __restrict__ Cf, u16* __restrict__ Cb,
             int M, int N, int K)
{
    __shared__ __align__(16) u16 lA[128 * 64];
    __shared__ __align__(16) u16 lB[128 * 64];

    const int tid  = threadIdx.x;
    const int lane = tid & 63;
    const int w    = tid >> 6;
    const int wr   = w >> 1;
    const int wc   = w & 1;
    const int m0   = blockIdx.y * 128;
    const int n0   = blockIdx.x * 128;

    const int lrow = lane & 15;
    const int kgrp = lane >> 4;

    f32x4 acc[4][4] = {};

    for (int k0 = 0; k0 < K; k0 += 64) {
        #pragma unroll
        for (int s = 0; s < 4; ++s) {
            int seg = w * 4 + s;
            int g   = seg * 64 + lane;
            int row = g >> 3;
            int kk  = (g & 7) * 8;
            const u16* gA = A + (size_t)(m0 + row) * K + k0 + kk;
            const u16* gB = W + (size_t)(n0 + row) * K + k0 + kk;
            __builtin_amdgcn_global_load_lds((GLOBAL_AS const void*)gA,
                                             (LDS_AS void*)(&lA[seg * 512]), 16, 0, 0);
            __builtin_amdgcn_global_load_lds((GLOBAL_AS const void*)gB,
                                             (LDS_AS void*)(&lB[seg * 512]), 16, 0, 0);
        }
        __syncthreads();
        #pragma unroll
        for (int kk = 0; kk < 64; kk += 32) {
            bf16x8 af[4], bfr[4];
            #pragma unroll
            for (int i = 0; i < 4; ++i) {
                int ar = wr * 64 + i * 16 + lrow;
                af[i]  = *(const bf16x8*)&lA[ar * 64 + kk + kgrp * 8];
                int br = wc * 64 + i * 16 + lrow;
                bfr[i] = *(const bf16x8*)&lB[br * 64 + kk + kgrp * 8];
            }
            #pragma unroll
            for (int mi = 0; mi < 4; ++mi)
                #pragma unroll
                for (int ni = 0; ni < 4; ++ni)
                    acc[mi][ni] = __builtin_amdgcn_mfma_f32_16x16x32_bf16(
                        af[mi], bfr[ni], acc[mi][ni], 0, 0, 0);
        }
        __syncthreads();
    }

    #pragma unroll
    for (int mi = 0; mi < 4; ++mi) {
        #pragma unroll
        for (int ni = 0; ni < 4; ++ni) {
            int gcol = n0 + wc * 64 + ni * 16 + lrow;
            float bv = bias ? bias[gcol] : 0.f;
            #pragma unroll
            for (int r = 0; r < 4; ++r) {
                int grow = m0 + wr * 64 + mi * 16 + kgrp * 4 + r;
                float v = acc[mi][ni][r] + bv;
                if (LEAKY) v = (v >= 0.f) ? v : 0.02f * v;
                size_t oidx;
                if (REMAP) {
                    int bb = grow & 511, tt = grow >> 9;
                    oidx = ((size_t)bb * 28 + tt) * (size_t)N + gcol;
                } else {
                    oidx = (size_t)grow * (size_t)N + gcol;
                }
                if (Cf) Cf[oidx] = v;
                if (Cb) Cb[oidx] = f2b(v);
            }
        }
    }
}

// ---------------------------------------------------------------------------
// Pipelined 256x256 logits GEMM — EXACT R11 config (measured 1152 µs total):
// quad-buffer depth-3, vmcnt(8), L2-blocked grid (8bx x 7by / XCD), nt stores.
// ---------------------------------------------------------------------------
__global__ __launch_bounds__(512)
void gemm_logits(const u16* __restrict__ A, const u16* __restrict__ W,
                 const float* __restrict__ bias, float* __restrict__ C,
                 int M, int N)
{
    constexpr int K = 512;
    __shared__ __align__(16) u16 lds[4 * 2 * 8192];

    const int tid  = threadIdx.x;
    const int lane = tid & 63;
    const int w    = tid >> 6;
    const int wr   = w >> 2;
    const int wc   = w & 3;
    const int l15  = lane & 15;
    const int kg   = lane >> 4;

    int id = blockIdx.x;
    int xcd = id & 7;
    int o   = id >> 3;
    int g, r;
    if (o < 840) { g = o / 56; r = o % 56; }
    else         { g = 15;     r = o - 840; }
    const int by = xcd * 7 + (r % 7);
    const int bx = g * 8 + (r / 7);
    const int m0 = by * 256;
    const int n0 = bx * 256;

    auto stage = [&](int kt, int buf) {
        #pragma unroll
        for (int ld = 0; ld < 2; ++ld) {
            int g2  = ld * 512 + tid;
            int row = g2 >> 2;
            int cp  = g2 & 3;
            int scp = cp ^ ((row >> 1) & 3);
            const u16* sA = A + (size_t)(m0 + row) * K + kt * 32 + scp * 8;
            const u16* sB = W + (size_t)(n0 + row) * K + kt * 32 + scp * 8;
            u32 dst = (u32)buf * 32768u + (u32)(ld * 512 + w * 64) * 16u;
            __builtin_amdgcn_global_load_lds((GLOBAL_AS const void*)sA,
                (LDS_AS void*)((char*)lds + dst), 16, 0, 0);
            __builtin_amdgcn_global_load_lds((GLOBAL_AS const void*)sB,
                (LDS_AS void*)((char*)lds + dst + 16384u), 16, 0, 0);
        }
    };

    f32x4 acc[8][4] = {};

    auto compute = [&](int buf) {
        const char* base = (const char*)lds + buf * 32768;
        bf16x8 a[8], b[4];
        #pragma unroll
        for (int mi = 0; mi < 8; ++mi) {
            int rr = wr * 128 + mi * 16 + l15;
            a[mi] = *(const bf16x8*)(base + rr * 64 + ((kg ^ ((rr >> 1) & 3)) << 4));
        }
        #pragma unroll
        for (int ni = 0; ni < 4; ++ni) {
            int rr = wc * 64 + ni * 16 + l15;
            b[ni] = *(const bf16x8*)(base + 16384 + rr * 64 + ((kg ^ ((rr >> 1) & 3)) << 4));
        }
        __builtin_amdgcn_s_setprio(1);
        #pragma unroll
        for (int mi = 0; mi < 8; ++mi)
            #pragma unroll
            for (int ni = 0; ni < 4; ++ni)
                acc[mi][ni] = __builtin_amdgcn_mfma_f32_16x16x32_bf16(
                    a[mi], b[ni], acc[mi][ni], 0, 0, 0);
        __builtin_amdgcn_s_setprio(0);
    };

    stage(0, 0);
    stage(1, 1);
    stage(2, 2);

    #pragma unroll 1
    for (int kt = 0; kt < 13; ++kt) {
        asm volatile("s_waitcnt vmcnt(8)" ::: "memory");
        __builtin_amdgcn_sched_barrier(0);
        __builtin_amdgcn_s_barrier();
        asm volatile("" ::: "memory");
        __builtin_amdgcn_sched_barrier(0);
        stage(kt + 3, (kt + 3) & 3);
        compute(kt & 3);
    }
    asm volatile("s_waitcnt vmcnt(8)" ::: "memory");
    __builtin_amdgcn_sched_barrier(0);
    __builtin_amdgcn_s_barrier();
    asm volatile("" ::: "memory");
    __builtin_amdgcn_sched_barrier(0);
    compute(1);
    asm volatile("s_waitcnt vmcnt(4)" ::: "memory");
    __builtin_amdgcn_sched_barrier(0);
    __builtin_amdgcn_s_barrier();
    asm volatile("" ::: "memory");
    __builtin_amdgcn_sched_barrier(0);
    compute(2);
    asm volatile("s_waitcnt vmcnt(0)" ::: "memory");
    __builtin_amdgcn_sched_barrier(0);
    __builtin_amdgcn_s_barrier();
    asm volatile("" ::: "memory");
    __builtin_amdgcn_sched_barrier(0);
    compute(3);

    #pragma unroll
    for (int ni = 0; ni < 4; ++ni) {
        int gcol = n0 + wc * 64 + ni * 16 + l15;
        float bv = bias[gcol];
        #pragma unroll
        for (int mi = 0; mi < 8; ++mi) {
            #pragma unroll
            for (int r = 0; r < 4; ++r) {
                int grow = m0 + wr * 128 + mi * 16 + kg * 4 + r;
                __builtin_nontemporal_store(acc[mi][ni][r] + bv,
                                            &C[(size_t)grow * (size_t)N + gcol]);
            }
        }
    }
}

// ---------------------------------------------------------------------------
// Fused GRU scan step — R12 variant (Whh B-frags direct from L2), kept for
// attribution. outs is the BASE pointer; kernel indexes slab t internally.
// ---------------------------------------------------------------------------
template<bool IS_DEC>
__global__ __launch_bounds__(256)
void scan_step(const u16* __restrict__ gi,
               const u16* __restrict__ Whh,
               const float* __restrict__ bhh,
               const u16* __restrict__ hprev_b,
               const float* __restrict__ hprev_f,
               u16* __restrict__ hnext_b,
               float* __restrict__ hnext_f,
               const int* __restrict__ xlens,
               u16* __restrict__ ctx,
               u16* __restrict__ outs,
               int t)
{
    __shared__ __align__(16) u16 lA[32 * 512];   // 32 KB h tile

    const int tid  = threadIdx.x;
    const int lane = tid & 63;
    const int w    = tid >> 6;
    const int rh   = w >> 1;
    const int jh   = w & 1;
    const int bc   = blockIdx.x >> 4;
    const int jc   = blockIdx.x & 15;

    const int l15 = lane & 15;
    const int kg  = lane >> 4;

    #pragma unroll
    for (int s = 0; s < 8; ++s) {
        int g   = s * 256 + tid;
        int row = g >> 6;
        int cp  = g & 63;
        const u16* src = hprev_b + (size_t)(bc * 32 + row) * 512
                                 + (size_t)((cp ^ (row & 7)) * 8);
        __builtin_amdgcn_global_load_lds((GLOBAL_AS const void*)src,
            (LDS_AS void*)((char*)lA + (s * 256 + w * 64) * 16), 16, 0, 0);
    }

    const int jloc = jh * 16 + l15;
    const int j    = jc * 32 + jloc;
    const int rowb = bc * 32 + rh * 16 + kg * 4;
    const float bhr = bhh[j], bhz = bhh[512 + j], bhn = bhh[1024 + j];

    const u16* gi_t = IS_DEC ? gi : gi + (size_t)t * 512 * 1536;
    float gir[4], giz[4], gin[4], hold[4];
    int   xl[4];
    #pragma unroll
    for (int r = 0; r < 4; ++r) {
        int row = rowb + r;
        gir[r]  = b2f(gi_t[row * 1536 + j]);
        giz[r]  = b2f(gi_t[row * 1536 + 512 + j]);
        gin[r]  = b2f(gi_t[row * 1536 + 1024 + j]);
        hold[r] = hprev_f[row * 512 + j];
        if (!IS_DEC) xl[r] = xlens[row];
    }
    __syncthreads();

    f32x4 acc[3] = {};
    const int arow = rh * 16 + l15;
    #pragma unroll 4
    for (int kc = 0; kc < 16; ++kc) {
        int k2 = kc * 64 + kg * 16;
        bf16x8 a = *(const bf16x8*)((const char*)lA + arow * 1024
                                    + (k2 ^ ((arow & 7) << 4)));
        #pragma unroll
        for (int g3 = 0; g3 < 3; ++g3) {
            const bf16x8 b = *(const bf16x8*)(Whh
                + (size_t)(g3 * 512 + jc * 32 + jloc) * 512 + kc * 32 + kg * 8);
            acc[g3] = __builtin_amdgcn_mfma_f32_16x16x32_bf16(a, b, acc[g3], 0, 0, 0);
        }
    }

    #pragma unroll
    for (int r = 0; r < 4; ++r) {
        int row = rowb + r;
        float rg = sigm(gir[r] + acc[0][r] + bhr);
        float zg = sigm(giz[r] + acc[1][r] + bhz);
        float ng = tanhf(gin[r] + rg * (acc[2][r] + bhn));
        float hn = (1.f - zg) * ng + zg * hold[r];
        hnext_f[row * 512 + j] = hn;
        hnext_b[row * 512 + j] = f2b(hn);
        if (IS_DEC) outs[((size_t)t * 512 + row) * 512 + j] = f2b(hn);
        else if (xl[r] - 1 == t) ctx[row * 1024 + j] = f2b(hn);
    }
}

// ---------------------------------------------------------------------------
// Embedding gather f32 -> bf16 (+ last valid token)
// ---------------------------------------------------------------------------
__global__ void embed_k(const int* __restrict__ x, const int* __restrict__ xlens,
                        const float* __restrict__ emb,
                        u16* __restrict__ embedded, u16* __restrict__ x_last)
{
    int id = blockIdx.x * 256 + threadIdx.x;
    if (id >= 28 * 512 * 128) return;
    int e2 = id & 127;
    int tb = id >> 7;
    int b  = tb & 511;
    int t  = tb >> 9;
    int tok = x[b * 28 + t];
    const float* src = emb + (size_t)tok * 256 + e2 * 2;
    u32 v = (u32)f2b(src[0]) | ((u32)f2b(src[1]) << 16);
    *(u32*)(embedded + (size_t)tb * 256 + e2 * 2) = v;
    if (t == xlens[b] - 1)
        *(u32*)(x_last + (size_t)b * 256 + e2 * 2) = v;
}

// ---------------------------------------------------------------------------
// Backward-direction context: single GRU step with h0 = 0.
// ---------------------------------------------------------------------------
__global__ void ctxb_k(const float* __restrict__ gi, const float* __restrict__ bhh,
                       u16* __restrict__ ctx)
{
    int idx = blockIdx.x * 256 + threadIdx.x;
    if (idx >= 512 * 512) return;
    int b = idx >> 9, j = idx & 511;
    int base = b * 1536;
    float r = sigm(gi[base + j] + bhh[j]);
    float z = sigm(gi[base + 512 + j] + bhh[512 + j]);
    float n = tanhf(gi[base + 1024 + j] + r * bhh[1024 + j]);
    ctx[b * 1024 + 512 + j] = f2b((1.f - z) * n);
}

// ---------------------------------------------------------------------------

extern "C" void kernel_launch(void* const* d_in, const int* in_sizes, int n_in,
                              void* d_out, int out_size, void* d_ws, size_t ws_size,
                              hipStream_t stream)
{
    const int*   x      = (const int*)d_in[0];
    const int*   xlens  = (const int*)d_in[1];
    const float* emb    = (const float*)d_in[2];
    const float* Wih_f  = (const float*)d_in[3];
    const float* Whh_f  = (const float*)d_in[4];
    const float* bih_f  = (const float*)d_in[5];
    const float* bhh_f  = (const float*)d_in[6];
    const float* Wih_b  = (const float*)d_in[7];
    const float* bih_b  = (const float*)d_in[9];
    const float* bhh_b  = (const float*)d_in[10];
    const float* fc1_w  = (const float*)d_in[11];
    const float* fc1_b  = (const float*)d_in[12];
    const float* fc2_w  = (const float*)d_in[13];
    const float* fc2_b  = (const float*)d_in[14];
    const float* dWih   = (const float*)d_in[15];
    const float* dWhh   = (const float*)d_in[16];
    const float* dbih   = (const float*)d_in[17];
    const float* dbhh   = (const float*)d_in[18];
    const float* re_w   = (const float*)d_in[19];
    const float* re_b   = (const float*)d_in[20];
    const float* hv_w   = (const float*)d_in[21];
    const float* hv_b   = (const float*)d_in[22];

    float* out        = (float*)d_out;
    float* out_logits = out;
    float* out_z      = out + (size_t)28 * 512 * 32000;
    float* out_re     = out_z + 512 * 128;

    char* ws = (char*)d_ws;
    size_t off = 0;
    auto alloc = [&](size_t bytes) -> void* {
        void* p = ws + off; off += (bytes + 255) & ~(size_t)255; return p;
    };
    u16* wWihf = (u16*)alloc(1536 * 256 * 2);
    u16* wWhhf = (u16*)alloc(1536 * 512 * 2);
    u16* wWihb = (u16*)alloc(1536 * 256 * 2);
    u16* wfc1  = (u16*)alloc(128 * 1024 * 2);
    u16* wfc2  = (u16*)alloc(512 * 128 * 2);
    u16* wdWih = (u16*)alloc(1536 * 512 * 2);
    u16* wdWhh = (u16*)alloc(1536 * 512 * 2);
    u16* wre   = (u16*)alloc(256 * 512 * 2);
    u16* whv   = (u16*)alloc((size_t)32000 * 512 * 2);
    u16*   hb0    = (u16*)  alloc(512 * 512 * 2);
    u16*   hb1    = (u16*)  alloc(512 * 512 * 2);
    float* hf0    = (float*)alloc(512 * 512 * 4);
    float* hf1    = (float*)alloc(512 * 512 * 4);
    u16*   ctx    = (u16*)  alloc(512 * 1024 * 2);
    float* gi_bw  = (float*)alloc(512 * 1536 * 4);
    u16*   out_zb = (u16*)  alloc(512 * 128 * 2);
    u16*   gi_dec = (u16*)  alloc(512 * 1536 * 2);
    u16*   outsb  = (u16*)  alloc((size_t)28 * 512 * 512 * 2);

    char* ds = (char*)d_out;
    size_t doff = 0;
    auto dalloc = [&](size_t bytes) -> void* {
        void* p = ds + doff; doff += (bytes + 255) & ~(size_t)255; return p;
    };
    u16* embedded = (u16*)dalloc((size_t)28 * 512 * 256 * 2);
    u16* x_last   = (u16*)dalloc(512 * 256 * 2);
    u16* gi_f     = (u16*)dalloc((size_t)28 * 512 * 1536 * 2);

    // 0. batched weight conversion + state init
    {
        CvtJobs jobs;
        const float* s[9] = { Wih_f, Whh_f, Wih_b, fc1_w, fc2_w, dWih, dWhh, re_w, hv_w };
        u16*         d[9] = { wWihf, wWhhf, wWihb, wfc1, wfc2, wdWih, wdWhh, wre, whv };
        int          n[9] = { 1536*256, 1536*512, 1536*256, 128*1024, 512*128,
                              1536*512, 1536*512, 256*512, 32000*512 };
        int cum = 0;
        for (int i = 0; i < 9; ++i) {
            jobs.src[i] = s[i]; jobs.dst[i] = d[i];
            cum += n[i] / 4; jobs.end4[i] = cum;
        }
        cvt_multi<<<2048, 256, 0, stream>>>(jobs, cum);
    }
    hipMemsetAsync(hb0, 0, 512 * 512 * 2, stream);
    hipMemsetAsync(hf0, 0, 512 * 512 * 4, stream);

    // 1. embedding gather
    embed_k<<<7168, 256, 0, stream>>>(x, xlens, emb, embedded, x_last);

    // 2. encoder input gates for all t
    gemm_bt<false, false><<<dim3(12, 112), 256, 0, stream>>>(
        embedded, wWihf, bih_f, nullptr, gi_f, 14336, 1536, 256);

    // 3. backward-direction context
    gemm_bt<false, false><<<dim3(12, 4), 256, 0, stream>>>(
        x_last, wWihb, bih_b, gi_bw, nullptr, 512, 1536, 256);
    ctxb_k<<<1024, 256, 0, stream>>>(gi_bw, bhh_b, ctx);

    // 4. forward encoder scan — one fused kernel per step
    {
        u16*   hb[2] = { hb0, hb1 };
        float* hf[2] = { hf0, hf1 };
        for (int t = 0; t < 28; ++t) {
            int s = t & 1, d = s ^ 1;
            scan_step<false><<<256, 256, 0, stream>>>(
                gi_f, wWhhf, bhh_f, hb[s], hf[s], hb[d], hf[d],
                xlens, ctx, nullptr, t);
        }
    }

    // 5. z = context @ fc1_w^T + fc1_b
    gemm_bt<false, false><<<dim3(1, 4), 256, 0, stream>>>(
        ctx, wfc1, fc1_b, out_z, out_zb, 512, 128, 1024);

    // 6. out0 = z @ fc2_w^T + fc2_b (f32 -> hf0, bf16 -> hb0)
    gemm_bt<false, false><<<dim3(4, 4), 256, 0, stream>>>(
        out_zb, wfc2, fc2_b, hf0, hb0, 512, 512, 128);

    // 7. decoder constant input gates
    gemm_bt<false, false><<<dim3(12, 4), 256, 0, stream>>>(
        hb0, wdWih, dbih, nullptr, gi_dec, 512, 1536, 512);

    // 8. decoder scan — one fused kernel per step (outs = BASE pointer)
    {
        u16*   hb[2] = { hb0, hb1 };
        float* hf[2] = { hf0, hf1 };
        for (int t = 0; t < 28; ++t) {
            int s = t & 1, d = s ^ 1;
            scan_step<true><<<256, 256, 0, stream>>>(
                gi_dec, wdWhh, dbhh, hb[s], hf[s], hb[d], hf[d],
                nullptr, nullptr, outsb, t);
        }
    }

    // 9. re_emb
    gemm_bt<true, true><<<dim3(2, 112), 256, 0, stream>>>(
        outsb, wre, re_b, out_re, nullptr, 14336, 256, 512);

    // 10. logits — EXACT R11 kernel (measured-best config)
    gemm_logits<<<7000, 512, 0, stream>>>(
        outsb, whv, hv_b, out_logits, 14336, 32000);
}

// Round 14
// 1070.672 us; speedup vs baseline: 1.2545x; 1.2545x over previous
//
#include <hip/hip_runtime.h>

typedef unsigned short u16;
typedef unsigned int u32;
typedef __attribute__((ext_vector_type(8))) short bf16x8;
typedef __attribute__((ext_vector_type(4))) float f32x4;

#define GLOBAL_AS __attribute__((address_space(1)))
#define LDS_AS __attribute__((address_space(3)))

__device__ __forceinline__ float b2f(u16 u) {
    union { float f; u32 i; } v; v.i = ((u32)u) << 16; return v.f;
}
__device__ __forceinline__ u16 f2b(float f) {
    union { float f; u32 i; } v; v.f = f;
    u32 i = v.i;
    u32 r = (i + 0x7FFFu + ((i >> 16) & 1u)) >> 16;
    return (u16)r;
}
__device__ __forceinline__ float sigm(float x) { return 1.f / (1.f + expf(-x)); }

// ---------------------------------------------------------------------------
// Batched f32 -> bf16 converter: 9 segments in one launch (verified R8)
// ---------------------------------------------------------------------------
struct CvtJobs {
    const float* src[9];
    u16*         dst[9];
    int          end4[9];
};
__global__ void cvt_multi(CvtJobs jobs, int total4)
{
    for (int id = blockIdx.x * 256 + threadIdx.x; id < total4;
         id += gridDim.x * 256) {
        int s = 0;
        while (id >= jobs.end4[s]) ++s;
        int base = (s == 0) ? 0 : jobs.end4[s - 1];
        int i = id - base;
        float4 v = ((const float4*)jobs.src[s])[i];
        u32 w0 = (u32)f2b(v.x) | ((u32)f2b(v.y) << 16);
        u32 w1 = (u32)f2b(v.z) | ((u32)f2b(v.w) << 16);
        ((u32*)jobs.dst[s])[i * 2]     = w0;
        ((u32*)jobs.dst[s])[i * 2 + 1] = w1;
    }
}

// ---------------------------------------------------------------------------
// Generic GEMM: C[M,N] = A[M,K] @ W[N,K]^T + bias[N]   (m97-pattern, verified)
// ---------------------------------------------------------------------------
template<bool LEAKY, bool REMAP>
__global__ __launch_bounds__(256)
void gemm_bt(const u16* __restrict__ A, const u16* __restrict__ W,
             const float* __restrict__ bias,
             float* __restrict__ Cf, u16* __restrict__ Cb,
             int M, int N, int K)
{
    __shared__ __align__(16) u16 lA[128 * 64];
    __shared__ __align__(16) u16 lB[128 * 64];

    const int tid  = threadIdx.x;
    const int lane = tid & 63;
    const int w    = tid >> 6;
    const int wr   = w >> 1;
    const int wc   = w & 1;
    const int m0   = blockIdx.y * 128;
    const int n0   = blockIdx.x * 128;

    const int lrow = lane & 15;
    const int kgrp = lane >> 4;

    f32x4 acc[4][4] = {};

    for (int k0 = 0; k0 < K; k0 += 64) {
        #pragma unroll
        for (int s = 0; s < 4; ++s) {
            int seg = w * 4 + s;
            int g   = seg * 64 + lane;
            int row = g >> 3;
            int kk  = (g & 7) * 8;
            const u16* gA = A + (size_t)(m0 + row) * K + k0 + kk;
            const u16* gB = W + (size_t)(n0 + row) * K + k0 + kk;
            __builtin_amdgcn_global_load_lds((GLOBAL_AS const void*)gA,
                                             (LDS_AS void*)(&lA[seg * 512]), 16, 0, 0);
            __builtin_amdgcn_global_load_lds((GLOBAL_AS const void*)gB,
                                             (LDS_AS void*)(&lB[seg * 512]), 16, 0, 0);
        }
        __syncthreads();
        #pragma unroll
        for (int kk = 0; kk < 64; kk += 32) {
            bf16x8 af[4], bfr[4];
            #pragma unroll
            for (int i = 0; i < 4; ++i) {
                int ar = wr * 64 + i * 16 + lrow;
                af[i]  = *(const bf16x8*)&lA[ar * 64 + kk + kgrp * 8];
                int br = wc * 64 + i * 16 + lrow;
                bfr[i] = *(const bf16x8*)&lB[br * 64 + kk + kgrp * 8];
            }
            #pragma unroll
            for (int mi = 0; mi < 4; ++mi)
                #pragma unroll
                for (int ni = 0; ni < 4; ++ni)
                    acc[mi][ni] = __builtin_amdgcn_mfma_f32_16x16x32_bf16(
                        af[mi], bfr[ni], acc[mi][ni], 0, 0, 0);
        }
        __syncthreads();
    }

    #pragma unroll
    for (int mi = 0; mi < 4; ++mi) {
        #pragma unroll
        for (int ni = 0; ni < 4; ++ni) {
            int gcol = n0 + wc * 64 + ni * 16 + lrow;
            float bv = bias ? bias[gcol] : 0.f;
            #pragma unroll
            for (int r = 0; r < 4; ++r) {
                int grow = m0 + wr * 64 + mi * 16 + kgrp * 4 + r;
                float v = acc[mi][ni][r] + bv;
                if (LEAKY) v = (v >= 0.f) ? v : 0.02f * v;
                size_t oidx;
                if (REMAP) {
                    int bb = grow & 511, tt = grow >> 9;
                    oidx = ((size_t)bb * 28 + tt) * (size_t)N + gcol;
                } else {
                    oidx = (size_t)grow * (size_t)N + gcol;
                }
                if (Cf) Cf[oidx] = v;
                if (Cb) Cb[oidx] = f2b(v);
            }
        }
    }
}

// ---------------------------------------------------------------------------
// Logits GEMM v3 (EXACT R12 kernel — measured −85 µs vs quad-256²):
// 128x256 tile, 8 waves (64x64/wave), BK=32 double-buffer, vmcnt(3),
// __launch_bounds__(512,4) -> 2 blocks/CU, L2-blocked grid, nt stores.
// ---------------------------------------------------------------------------
__global__ __launch_bounds__(512, 4)
void gemm_logits(const u16* __restrict__ A, const u16* __restrict__ W,
                 const float* __restrict__ bias, float* __restrict__ C,
                 int M, int N)
{
    constexpr int K = 512;
    __shared__ __align__(16) u16 lds[2 * 12288];   // 2 bufs x (A 8KB + B 16KB)

    const int tid  = threadIdx.x;
    const int lane = tid & 63;
    const int w    = tid >> 6;          // 0..7
    const int wr   = w >> 2;            // 0..1: 64-row half of 128
    const int wc   = w & 3;             // 0..3: 64-col quarter of 256
    const int l15  = lane & 15;
    const int kg   = lane >> 4;

    // L2-blocked bijective mapping: grid 14000 = 8 XCD x 1750.
    int id  = blockIdx.x;
    int xcd = id & 7;
    int o   = id >> 3;
    int g, r;
    if (o < 1680) { g = o / 112; r = o % 112; }
    else          { g = 15;      r = o - 1680; }
    const int by = xcd * 14 + (r % 14);
    const int bx = g * 8 + (r / 14);
    const int m0 = by * 128;
    const int n0 = bx * 256;

    auto stage = [&](int kt, int buf) {
        {
            int row = tid >> 2, cp = tid & 3;
            int scp = cp ^ ((row >> 1) & 3);
            const u16* sA = A + (size_t)(m0 + row) * K + kt * 32 + scp * 8;
            u32 dst = (u32)buf * 24576u + (u32)(w * 64) * 16u;
            __builtin_amdgcn_global_load_lds((GLOBAL_AS const void*)sA,
                (LDS_AS void*)((char*)lds + dst), 16, 0, 0);
        }
        #pragma unroll
        for (int ld = 0; ld < 2; ++ld) {
            int gch = ld * 512 + tid;   // 0..1023
            int row = gch >> 2, cp = gch & 3;
            int scp = cp ^ ((row >> 1) & 3);
            const u16* sB = W + (size_t)(n0 + row) * K + kt * 32 + scp * 8;
            u32 dst = (u32)buf * 24576u + 8192u + (u32)(ld * 512 + w * 64) * 16u;
            __builtin_amdgcn_global_load_lds((GLOBAL_AS const void*)sB,
                (LDS_AS void*)((char*)lds + dst), 16, 0, 0);
        }
    };

    f32x4 acc[4][4] = {};

    stage(0, 0);
    stage(1, 1);

    #pragma unroll 1
    for (int kt = 0; kt < 16; ++kt) {
        if (kt < 15) { asm volatile("s_waitcnt vmcnt(3)" ::: "memory"); }
        else         { asm volatile("s_waitcnt vmcnt(0)" ::: "memory"); }
        __builtin_amdgcn_sched_barrier(0);
        __builtin_amdgcn_s_barrier();
        asm volatile("" ::: "memory");
        __builtin_amdgcn_sched_barrier(0);

        const char* base = (const char*)lds + (kt & 1) * 24576;
        bf16x8 a[4], b[4];
        #pragma unroll
        for (int mi = 0; mi < 4; ++mi) {
            int rr = wr * 64 + mi * 16 + l15;
            a[mi] = *(const bf16x8*)(base + rr * 64 + ((kg ^ ((rr >> 1) & 3)) << 4));
        }
        #pragma unroll
        for (int ni = 0; ni < 4; ++ni) {
            int rb = wc * 64 + ni * 16 + l15;
            b[ni] = *(const bf16x8*)(base + 8192 + rb * 64 + ((kg ^ ((rb >> 1) & 3)) << 4));
        }
        if (kt < 14) {
            __syncthreads();            // all waves' ds_reads done -> buffer free
            stage(kt + 2, kt & 1);
        }
        __builtin_amdgcn_s_setprio(1);
        #pragma unroll
        for (int mi = 0; mi < 4; ++mi)
            #pragma unroll
            for (int ni = 0; ni < 4; ++ni)
                acc[mi][ni] = __builtin_amdgcn_mfma_f32_16x16x32_bf16(
                    a[mi], b[ni], acc[mi][ni], 0, 0, 0);
        __builtin_amdgcn_s_setprio(0);
    }

    #pragma unroll
    for (int ni = 0; ni < 4; ++ni) {
        int gcol = n0 + wc * 64 + ni * 16 + l15;
        float bv = bias[gcol];
        #pragma unroll
        for (int mi = 0; mi < 4; ++mi) {
            #pragma unroll
            for (int r = 0; r < 4; ++r) {
                int grow = m0 + wr * 64 + mi * 16 + kg * 4 + r;
                __builtin_nontemporal_store(acc[mi][ni][r] + bv,
                                            &C[(size_t)grow * (size_t)N + gcol]);
            }
        }
    }
}

// ---------------------------------------------------------------------------
// Fused GRU scan step — EXACT R5/R11 kernel (LDS-staged Whh; measured-best).
// outs is the BASE pointer; kernel indexes slab t internally.
// ---------------------------------------------------------------------------
template<bool IS_DEC>
__global__ __launch_bounds__(256)
void scan_step(const u16* __restrict__ gi,
               const u16* __restrict__ Whh,
               const float* __restrict__ bhh,
               const u16* __restrict__ hprev_b,
               const float* __restrict__ hprev_f,
               u16* __restrict__ hnext_b,
               float* __restrict__ hnext_f,
               const int* __restrict__ xlens,
               u16* __restrict__ ctx,
               u16* __restrict__ outs,
               int t)
{
    __shared__ __align__(16) u16 lB[96 * 512];
    __shared__ __align__(16) u16 lA[32 * 512];

    const int tid  = threadIdx.x;
    const int lane = tid & 63;
    const int w    = tid >> 6;
    const int rh   = w >> 1;
    const int jh   = w & 1;
    const int bc   = blockIdx.x >> 4;
    const int jc   = blockIdx.x & 15;

    const int l15 = lane & 15;
    const int kg  = lane >> 4;

    #pragma unroll
    for (int s = 0; s < 24; ++s) {
        int g    = s * 256 + tid;
        int rr   = g >> 6;
        int cp   = g & 63;
        int gate = rr >> 5;
        int c    = rr & 31;
        int whrow = gate * 512 + jc * 32 + c;
        const u16* src = Whh + (size_t)whrow * 512 + (size_t)((cp ^ (rr & 7)) * 8);
        __builtin_amdgcn_global_load_lds((GLOBAL_AS const void*)src,
            (LDS_AS void*)((char*)lB + (s * 256 + w * 64) * 16), 16, 0, 0);
    }
    #pragma unroll
    for (int s = 0; s < 8; ++s) {
        int g   = s * 256 + tid;
        int row = g >> 6;
        int cp  = g & 63;
        const u16* src = hprev_b + (size_t)(bc * 32 + row) * 512
                                 + (size_t)((cp ^ (row & 7)) * 8);
        __builtin_amdgcn_global_load_lds((GLOBAL_AS const void*)src,
            (LDS_AS void*)((char*)lA + (s * 256 + w * 64) * 16), 16, 0, 0);
    }

    const int jloc = jh * 16 + l15;
    const int j    = jc * 32 + jloc;
    const int rowb = bc * 32 + rh * 16 + kg * 4;
    const float bhr = bhh[j], bhz = bhh[512 + j], bhn = bhh[1024 + j];

    const u16* gi_t = IS_DEC ? gi : gi + (size_t)t * 512 * 1536;
    float gir[4], giz[4], gin[4], hold[4];
    int   xl[4];
    #pragma unroll
    for (int r = 0; r < 4; ++r) {
        int row = rowb + r;
        gir[r]  = b2f(gi_t[row * 1536 + j]);
        giz[r]  = b2f(gi_t[row * 1536 + 512 + j]);
        gin[r]  = b2f(gi_t[row * 1536 + 1024 + j]);
        hold[r] = hprev_f[row * 512 + j];
        if (!IS_DEC) xl[r] = xlens[row];
    }
    __syncthreads();

    f32x4 acc[3] = {};
    const int arow = rh * 16 + l15;
    #pragma unroll 4
    for (int kc = 0; kc < 16; ++kc) {
        int k2 = kc * 64 + kg * 16;
        bf16x8 a = *(const bf16x8*)((const char*)lA + arow * 1024
                                    + (k2 ^ ((arow & 7) << 4)));
        #pragma unroll
        for (int g3 = 0; g3 < 3; ++g3) {
            int rr = g3 * 32 + jloc;
            bf16x8 b = *(const bf16x8*)((const char*)lB + rr * 1024
                                        + (k2 ^ ((rr & 7) << 4)));
            acc[g3] = __builtin_amdgcn_mfma_f32_16x16x32_bf16(a, b, acc[g3], 0, 0, 0);
        }
    }

    #pragma unroll
    for (int r = 0; r < 4; ++r) {
        int row = rowb + r;
        float rg = sigm(gir[r] + acc[0][r] + bhr);
        float zg = sigm(giz[r] + acc[1][r] + bhz);
        float ng = tanhf(gin[r] + rg * (acc[2][r] + bhn));
        float hn = (1.f - zg) * ng + zg * hold[r];
        hnext_f[row * 512 + j] = hn;
        hnext_b[row * 512 + j] = f2b(hn);
        if (IS_DEC) outs[((size_t)t * 512 + row) * 512 + j] = f2b(hn);
        else if (xl[r] - 1 == t) ctx[row * 1024 + j] = f2b(hn);
    }
}

// ---------------------------------------------------------------------------
// Embedding gather f32 -> bf16 (+ last valid token)
// ---------------------------------------------------------------------------
__global__ void embed_k(const int* __restrict__ x, const int* __restrict__ xlens,
                        const float* __restrict__ emb,
                        u16* __restrict__ embedded, u16* __restrict__ x_last)
{
    int id = blockIdx.x * 256 + threadIdx.x;
    if (id >= 28 * 512 * 128) return;
    int e2 = id & 127;
    int tb = id >> 7;
    int b  = tb & 511;
    int t  = tb >> 9;
    int tok = x[b * 28 + t];
    const float* src = emb + (size_t)tok * 256 + e2 * 2;
    u32 v = (u32)f2b(src[0]) | ((u32)f2b(src[1]) << 16);
    *(u32*)(embedded + (size_t)tb * 256 + e2 * 2) = v;
    if (t == xlens[b] - 1)
        *(u32*)(x_last + (size_t)b * 256 + e2 * 2) = v;
}

// ---------------------------------------------------------------------------
// Backward-direction context: single GRU step with h0 = 0.
// ---------------------------------------------------------------------------
__global__ void ctxb_k(const float* __restrict__ gi, const float* __restrict__ bhh,
                       u16* __restrict__ ctx)
{
    int idx = blockIdx.x * 256 + threadIdx.x;
    if (idx >= 512 * 512) return;
    int b = idx >> 9, j = idx & 511;
    int base = b * 1536;
    float r = sigm(gi[base + j] + bhh[j]);
    float z = sigm(gi[base + 512 + j] + bhh[512 + j]);
    float n = tanhf(gi[base + 1024 + j] + r * bhh[1024 + j]);
    ctx[b * 1024 + 512 + j] = f2b((1.f - z) * n);
}

// ---------------------------------------------------------------------------

extern "C" void kernel_launch(void* const* d_in, const int* in_sizes, int n_in,
                              void* d_out, int out_size, void* d_ws, size_t ws_size,
                              hipStream_t stream)
{
    const int*   x      = (const int*)d_in[0];
    const int*   xlens  = (const int*)d_in[1];
    const float* emb    = (const float*)d_in[2];
    const float* Wih_f  = (const float*)d_in[3];
    const float* Whh_f  = (const float*)d_in[4];
    const float* bih_f  = (const float*)d_in[5];
    const float* bhh_f  = (const float*)d_in[6];
    const float* Wih_b  = (const float*)d_in[7];
    const float* bih_b  = (const float*)d_in[9];
    const float* bhh_b  = (const float*)d_in[10];
    const float* fc1_w  = (const float*)d_in[11];
    const float* fc1_b  = (const float*)d_in[12];
    const float* fc2_w  = (const float*)d_in[13];
    const float* fc2_b  = (const float*)d_in[14];
    const float* dWih   = (const float*)d_in[15];
    const float* dWhh   = (const float*)d_in[16];
    const float* dbih   = (const float*)d_in[17];
    const float* dbhh   = (const float*)d_in[18];
    const float* re_w   = (const float*)d_in[19];
    const float* re_b   = (const float*)d_in[20];
    const float* hv_w   = (const float*)d_in[21];
    const float* hv_b   = (const float*)d_in[22];

    float* out        = (float*)d_out;
    float* out_logits = out;
    float* out_z      = out + (size_t)28 * 512 * 32000;
    float* out_re     = out_z + 512 * 128;

    char* ws = (char*)d_ws;
    size_t off = 0;
    auto alloc = [&](size_t bytes) -> void* {
        void* p = ws + off; off += (bytes + 255) & ~(size_t)255; return p;
    };
    u16* wWihf = (u16*)alloc(1536 * 256 * 2);
    u16* wWhhf = (u16*)alloc(1536 * 512 * 2);
    u16* wWihb = (u16*)alloc(1536 * 256 * 2);
    u16* wfc1  = (u16*)alloc(128 * 1024 * 2);
    u16* wfc2  = (u16*)alloc(512 * 128 * 2);
    u16* wdWih = (u16*)alloc(1536 * 512 * 2);
    u16* wdWhh = (u16*)alloc(1536 * 512 * 2);
    u16* wre   = (u16*)alloc(256 * 512 * 2);
    u16* whv   = (u16*)alloc((size_t)32000 * 512 * 2);
    u16*   hb0    = (u16*)  alloc(512 * 512 * 2);
    u16*   hb1    = (u16*)  alloc(512 * 512 * 2);
    float* hf0    = (float*)alloc(512 * 512 * 4);
    float* hf1    = (float*)alloc(512 * 512 * 4);
    u16*   ctx    = (u16*)  alloc(512 * 1024 * 2);
    float* gi_bw  = (float*)alloc(512 * 1536 * 4);
    u16*   out_zb = (u16*)  alloc(512 * 128 * 2);
    u16*   gi_dec = (u16*)  alloc(512 * 1536 * 2);
    u16*   outsb  = (u16*)  alloc((size_t)28 * 512 * 512 * 2);

    char* ds = (char*)d_out;
    size_t doff = 0;
    auto dalloc = [&](size_t bytes) -> void* {
        void* p = ds + doff; doff += (bytes + 255) & ~(size_t)255; return p;
    };
    u16* embedded = (u16*)dalloc((size_t)28 * 512 * 256 * 2);
    u16* x_last   = (u16*)dalloc(512 * 256 * 2);
    u16* gi_f     = (u16*)dalloc((size_t)28 * 512 * 1536 * 2);

    // 0. batched weight conversion + state init
    {
        CvtJobs jobs;
        const float* s[9] = { Wih_f, Whh_f, Wih_b, fc1_w, fc2_w, dWih, dWhh, re_w, hv_w };
        u16*         d[9] = { wWihf, wWhhf, wWihb, wfc1, wfc2, wdWih, wdWhh, wre, whv };
        int          n[9] = { 1536*256, 1536*512, 1536*256, 128*1024, 512*128,
                              1536*512, 1536*512, 256*512, 32000*512 };
        int cum = 0;
        for (int i = 0; i < 9; ++i) {
            jobs.src[i] = s[i]; jobs.dst[i] = d[i];
            cum += n[i] / 4; jobs.end4[i] = cum;
        }
        cvt_multi<<<2048, 256, 0, stream>>>(jobs, cum);
    }
    hipMemsetAsync(hb0, 0, 512 * 512 * 2, stream);
    hipMemsetAsync(hf0, 0, 512 * 512 * 4, stream);

    // 1. embedding gather
    embed_k<<<7168, 256, 0, stream>>>(x, xlens, emb, embedded, x_last);

    // 2. encoder input gates for all t
    gemm_bt<false, false><<<dim3(12, 112), 256, 0, stream>>>(
        embedded, wWihf, bih_f, nullptr, gi_f, 14336, 1536, 256);

    // 3. backward-direction context
    gemm_bt<false, false><<<dim3(12, 4), 256, 0, stream>>>(
        x_last, wWihb, bih_b, gi_bw, nullptr, 512, 1536, 256);
    ctxb_k<<<1024, 256, 0, stream>>>(gi_bw, bhh_b, ctx);

    // 4. forward encoder scan — one fused kernel per step
    {
        u16*   hb[2] = { hb0, hb1 };
        float* hf[2] = { hf0, hf1 };
        for (int t = 0; t < 28; ++t) {
            int s = t & 1, d = s ^ 1;
            scan_step<false><<<256, 256, 0, stream>>>(
                gi_f, wWhhf, bhh_f, hb[s], hf[s], hb[d], hf[d],
                xlens, ctx, nullptr, t);
        }
    }

    // 5. z = context @ fc1_w^T + fc1_b
    gemm_bt<false, false><<<dim3(1, 4), 256, 0, stream>>>(
        ctx, wfc1, fc1_b, out_z, out_zb, 512, 128, 1024);

    // 6. out0 = z @ fc2_w^T + fc2_b (f32 -> hf0, bf16 -> hb0)
    gemm_bt<false, false><<<dim3(4, 4), 256, 0, stream>>>(
        out_zb, wfc2, fc2_b, hf0, hb0, 512, 512, 128);

    // 7. decoder constant input gates
    gemm_bt<false, false><<<dim3(12, 4), 256, 0, stream>>>(
        hb0, wdWih, dbih, nullptr, gi_dec, 512, 1536, 512);

    // 8. decoder scan — one fused kernel per step (outs = BASE pointer)
    {
        u16*   hb[2] = { hb0, hb1 };
        float* hf[2] = { hf0, hf1 };
        for (int t = 0; t < 28; ++t) {
            int s = t & 1, d = s ^ 1;
            scan_step<true><<<256, 256, 0, stream>>>(
                gi_dec, wdWhh, dbhh, hb[s], hf[s], hb[d], hf[d],
                nullptr, nullptr, outsb, t);
        }
    }

    // 9. re_emb
    gemm_bt<true, true><<<dim3(2, 112), 256, 0, stream>>>(
        outsb, wre, re_b, out_re, nullptr, 14336, 256, 512);

    // 10. logits — v3 kernel (measured-best: −85 µs vs 256² quad)
    gemm_logits<<<14000, 512, 0, stream>>>(
        outsb, whv, hv_b, out_logits, 14336, 32000);
}